// Round 1
// baseline (3875.464 us; speedup 1.0000x reference)
//
#include <hip/hip_runtime.h>

#define B_N 32768
#define D_N 512
#define K_N 8192
#define EMA 0.99f
#define ONE_M_EMA 0.01f
#define EPS_ 1e-5f
#define CCOST 0.25f

// ws layout:
// [0, 262144)        : u64 packed[B_N]  (sortable_dist<<32 | idx), init 0xFF
// [262144, 294912)   : float wsq[K_N]
// [294912, 294916)   : float loss_sum
// [294916, 294920)   : float n_sum

// ---------------------------------------------------------------- prep ----
// wsq[k] = sum_d w[k,d]^2  (one wave per row), ncs_out = 0.99*ecs
__global__ __launch_bounds__(256) void prep_kernel(const float* __restrict__ w,
                                                   const float* __restrict__ ecs,
                                                   float* __restrict__ wsq,
                                                   float* __restrict__ ncs_out) {
  int row  = blockIdx.x * 4 + (threadIdx.x >> 6);
  int lane = threadIdx.x & 63;
  const float* p = w + (size_t)row * D_N + lane * 8;
  float4 a = *(const float4*)p;
  float4 b = *(const float4*)(p + 4);
  float s = a.x*a.x + a.y*a.y + a.z*a.z + a.w*a.w
          + b.x*b.x + b.y*b.y + b.z*b.z + b.w*b.w;
  #pragma unroll
  for (int off = 32; off; off >>= 1) s += __shfl_down(s, off);
  if (lane == 0) wsq[row] = s;

  int gid = blockIdx.x * 256 + threadIdx.x;
  if (gid < K_N) ncs_out[gid] = EMA * ecs[gid];
}

// nedw_out = 0.99 * ema_dw  (scatter adds 0.01*z later)
__global__ __launch_bounds__(256) void prep_nedw(const float4* __restrict__ edw,
                                                 float4* __restrict__ nedw) {
  int i = blockIdx.x * 256 + threadIdx.x;   // K_N*D_N/4 = 1048576 total
  float4 v = edw[i];
  v.x *= EMA; v.y *= EMA; v.z *= EMA; v.w *= EMA;
  nedw[i] = v;
}

// --------------------------------------------------------- score+argmin ---
// dist'[b,k] = wsq[k] - 2 * z[b]·w[k]   (|z|^2 dropped: argmin-invariant)
// 128x128 tile, 8x8 per thread, D staged in chunks of 16.
constexpr int TM = 128, TK = 128, DC = 16, KSPLIT = 4, KPB = K_N / KSPLIT;

__global__ __launch_bounds__(256, 2) void score_argmin(
    const float* __restrict__ z, const float* __restrict__ w,
    const float* __restrict__ wsq, unsigned long long* __restrict__ packed) {
  __shared__ float zs[DC][TM + 4];
  __shared__ float wsh[DC][TK + 4];
  __shared__ float wsqs[TK];
  __shared__ float redv[TM][17];
  __shared__ int   redi[TM][17];

  const int t  = threadIdx.x;
  const int tx = t & 15, ty = t >> 4;
  const int row0 = blockIdx.x * TM;
  const int ks0  = blockIdx.y * KPB;

  float minv[8];
  int   mini[8];
  #pragma unroll
  for (int i = 0; i < 8; i++) { minv[i] = 3.4e38f; mini[i] = 0; }

  const int lr = t >> 2;        // loader row 0..63
  const int ld = (t & 3) * 4;   // loader d-offset 0,4,8,12

  for (int kt = 0; kt < KPB; kt += TK) {
    const int c0 = ks0 + kt;
    __syncthreads();                       // protect wsqs/red reuse across tiles
    if (t < TK) wsqs[t] = wsq[c0 + t];

    float acc[8][8];
    #pragma unroll
    for (int i = 0; i < 8; i++)
      #pragma unroll
      for (int j = 0; j < 8; j++) acc[i][j] = 0.f;

    for (int d0 = 0; d0 < D_N; d0 += DC) {
      __syncthreads();
      float4 za1 = *(const float4*)&z[(size_t)(row0 + lr)      * D_N + d0 + ld];
      float4 za2 = *(const float4*)&z[(size_t)(row0 + lr + 64) * D_N + d0 + ld];
      float4 wa1 = *(const float4*)&w[(size_t)(c0 + lr)        * D_N + d0 + ld];
      float4 wa2 = *(const float4*)&w[(size_t)(c0 + lr + 64)   * D_N + d0 + ld];
      zs[ld+0][lr]    = za1.x; zs[ld+1][lr]    = za1.y; zs[ld+2][lr]    = za1.z; zs[ld+3][lr]    = za1.w;
      zs[ld+0][lr+64] = za2.x; zs[ld+1][lr+64] = za2.y; zs[ld+2][lr+64] = za2.z; zs[ld+3][lr+64] = za2.w;
      wsh[ld+0][lr]    = wa1.x; wsh[ld+1][lr]    = wa1.y; wsh[ld+2][lr]    = wa1.z; wsh[ld+3][lr]    = wa1.w;
      wsh[ld+0][lr+64] = wa2.x; wsh[ld+1][lr+64] = wa2.y; wsh[ld+2][lr+64] = wa2.z; wsh[ld+3][lr+64] = wa2.w;
      __syncthreads();
      #pragma unroll
      for (int j = 0; j < DC; j++) {
        float za[8], wb[8];
        *(float4*)&za[0] = *(const float4*)&zs[j][ty * 8];
        *(float4*)&za[4] = *(const float4*)&zs[j][ty * 8 + 4];
        *(float4*)&wb[0] = *(const float4*)&wsh[j][tx * 8];
        *(float4*)&wb[4] = *(const float4*)&wsh[j][tx * 8 + 4];
        #pragma unroll
        for (int ii = 0; ii < 8; ii++)
          #pragma unroll
          for (int jj = 0; jj < 8; jj++)
            acc[ii][jj] += za[ii] * wb[jj];
      }
    }
    #pragma unroll
    for (int ii = 0; ii < 8; ii++) {
      #pragma unroll
      for (int jj = 0; jj < 8; jj++) {
        float dist = wsqs[tx * 8 + jj] - 2.0f * acc[ii][jj];
        int c = c0 + tx * 8 + jj;
        if (dist < minv[ii]) { minv[ii] = dist; mini[ii] = c; }  // strict <: first idx wins
      }
    }
  }
  __syncthreads();
  #pragma unroll
  for (int ii = 0; ii < 8; ii++) { redv[ty*8+ii][tx] = minv[ii]; redi[ty*8+ii][tx] = mini[ii]; }
  __syncthreads();
  if (t < TM) {
    float bv = 3.4e38f; int bi = 0x7FFFFFFF;
    for (int x = 0; x < 16; x++) {
      float v = redv[t][x]; int c = redi[t][x];
      if (v < bv || (v == bv && c < bi)) { bv = v; bi = c; }
    }
    unsigned u = __float_as_uint(bv);
    u = (u & 0x80000000u) ? ~u : (u | 0x80000000u);     // total-order map
    unsigned long long key = ((unsigned long long)u << 32) | (unsigned)bi;
    atomicMin(&packed[row0 + t], key);                  // ties -> smaller idx
  }
}

// ------------------------------------------------- gather + loss + scatter -
__global__ __launch_bounds__(256) void gather_scatter(
    const float* __restrict__ z, const float* __restrict__ w,
    const unsigned long long* __restrict__ packed,
    float* __restrict__ qout, float* __restrict__ idxout,
    float* __restrict__ ncs_out, float* __restrict__ nedw_out,
    float* __restrict__ loss_sum) {
  int row = blockIdx.x;
  int t   = threadIdx.x;
  int idx = (int)(packed[row] & 0xFFFFFFFFull);
  float2 zv = *(const float2*)&z[(size_t)row * D_N + t * 2];
  float2 wv = *(const float2*)&w[(size_t)idx * D_N + t * 2];
  float2 q;
  q.x = zv.x + (wv.x - zv.x);     // match reference's straight-through f32 expr
  q.y = zv.y + (wv.y - zv.y);
  *(float2*)&qout[(size_t)row * D_N + t * 2] = q;
  float dx = zv.x - wv.x, dy = zv.y - wv.y;
  float s = dx*dx + dy*dy;
  #pragma unroll
  for (int off = 32; off; off >>= 1) s += __shfl_down(s, off);
  __shared__ float part[4];
  if ((t & 63) == 0) part[t >> 6] = s;
  __syncthreads();
  if (t == 0) {
    atomicAdd(loss_sum, part[0] + part[1] + part[2] + part[3]);
    atomicAdd(&ncs_out[idx], ONE_M_EMA);
    idxout[row] = (float)idx;
  }
  atomicAdd(&nedw_out[(size_t)idx * D_N + t*2],     ONE_M_EMA * zv.x);
  atomicAdd(&nedw_out[(size_t)idx * D_N + t*2 + 1], ONE_M_EMA * zv.y);
}

// ------------------------------------------------------------- reductions -
__global__ __launch_bounds__(256) void reduce_n(const float* __restrict__ ncs_out,
                                                float* __restrict__ nsum) {
  int t = threadIdx.x;
  float s = 0.f;
  for (int i = t; i < K_N; i += 256) s += ncs_out[i];
  #pragma unroll
  for (int off = 32; off; off >>= 1) s += __shfl_down(s, off);
  __shared__ float part[4];
  if ((t & 63) == 0) part[t >> 6] = s;
  __syncthreads();
  if (t == 0) nsum[0] = part[0] + part[1] + part[2] + part[3];
}

__global__ __launch_bounds__(256) void finalize(
    const float* __restrict__ ncs_out, const float* __restrict__ nedw_out,
    float* __restrict__ nw_out, const float* __restrict__ nsum,
    const float* __restrict__ loss_sum, float* __restrict__ loss_out) {
  size_t i = (size_t)blockIdx.x * 256 + threadIdx.x;   // over K_N*D_N
  float n = nsum[0];
  int k = (int)(i >> 9);
  float nv = ncs_out[k];
  float cs = (nv + EPS_) / (n + K_N * EPS_) * n;
  nw_out[i] = nedw_out[i] / cs;
  if (i == 0) loss_out[0] = CCOST * loss_sum[0] / (float)((size_t)B_N * D_N);
}

// ------------------------------------------------------------------ launch -
extern "C" void kernel_launch(void* const* d_in, const int* in_sizes, int n_in,
                              void* d_out, int out_size, void* d_ws, size_t ws_size,
                              hipStream_t stream) {
  const float* z   = (const float*)d_in[0];
  const float* w   = (const float*)d_in[1];
  const float* ecs = (const float*)d_in[2];
  const float* edw = (const float*)d_in[3];

  float* out      = (float*)d_out;
  float* qout     = out;                                   // B*D
  float* idxout   = out + (size_t)B_N * D_N;               // B
  float* loss_out = idxout + B_N;                          // 1
  float* nw_out   = loss_out + 1;                          // K*D
  float* ncs_out  = nw_out + (size_t)K_N * D_N;            // K
  float* nedw_out = ncs_out + K_N;                         // K*D

  unsigned long long* packed = (unsigned long long*)d_ws;
  float* wsq      = (float*)((char*)d_ws + 262144);
  float* loss_sum = (float*)((char*)d_ws + 294912);
  float* nsum     = loss_sum + 1;

  hipMemsetAsync(d_ws, 0xFF, 262144, stream);              // packed = +inf keys
  hipMemsetAsync((void*)loss_sum, 0, 8, stream);           // loss_sum, n_sum

  prep_kernel<<<2048, 256, 0, stream>>>(w, ecs, wsq, ncs_out);
  prep_nedw<<<4096, 256, 0, stream>>>((const float4*)edw, (float4*)nedw_out);
  score_argmin<<<dim3(B_N / TM, KSPLIT), 256, 0, stream>>>(z, w, wsq, packed);
  gather_scatter<<<B_N, 256, 0, stream>>>(z, w, packed, qout, idxout,
                                          ncs_out, nedw_out, loss_sum);
  reduce_n<<<1, 256, 0, stream>>>(ncs_out, nsum);
  finalize<<<K_N * D_N / 256, 256, 0, stream>>>(ncs_out, nedw_out, nw_out,
                                                nsum, loss_sum, loss_out);
}

// Round 2
// 1499.772 us; speedup vs baseline: 2.5840x; 2.5840x over previous
//
#include <hip/hip_runtime.h>

#define B_N 32768
#define D_N 512
#define K_N 8192
#define EMA 0.99f
#define ONE_M_EMA 0.01f
#define EPS_ 1e-5f
#define CCOST 0.25f

// ws layout:
// [0, 262144)        : u64 packed[B_N]  (sortable_dist<<32 | idx), init 0xFF
// [262144, 294912)   : float wsq[K_N]
// [294912, 294916)   : float loss_sum
// [294916, 294920)   : float n_sum

typedef __attribute__((ext_vector_type(8))) short bf16x8;
typedef __attribute__((ext_vector_type(4))) float f32x4;

// ---------------------------------------------------------------- prep ----
__global__ __launch_bounds__(256) void prep_kernel(const float* __restrict__ w,
                                                   const float* __restrict__ ecs,
                                                   float* __restrict__ wsq,
                                                   float* __restrict__ ncs_out) {
  int row  = blockIdx.x * 4 + (threadIdx.x >> 6);
  int lane = threadIdx.x & 63;
  const float* p = w + (size_t)row * D_N + lane * 8;
  float4 a = *(const float4*)p;
  float4 b = *(const float4*)(p + 4);
  float s = a.x*a.x + a.y*a.y + a.z*a.z + a.w*a.w
          + b.x*b.x + b.y*b.y + b.z*b.z + b.w*b.w;
  #pragma unroll
  for (int off = 32; off; off >>= 1) s += __shfl_down(s, off);
  if (lane == 0) wsq[row] = s;

  int gid = blockIdx.x * 256 + threadIdx.x;
  if (gid < K_N) ncs_out[gid] = EMA * ecs[gid];
}

__global__ __launch_bounds__(256) void prep_nedw(const float4* __restrict__ edw,
                                                 float4* __restrict__ nedw) {
  int i = blockIdx.x * 256 + threadIdx.x;
  float4 v = edw[i];
  v.x *= EMA; v.y *= EMA; v.z *= EMA; v.w *= EMA;
  nedw[i] = v;
}

// --------------------------------------------------------- score+argmin ---
// dist'[b,k] = wsq[k] - 2 * z[b]·w[k]   (|z|^2 dropped: argmin-invariant)
// bf16-split MFMA: z = zh+zl, w = wh+wl; dot ~= zh·wh + zh·wl + zl·wh
// 128x128 tile, BK=32, 4 waves (2x2 of 64x64), 48 MFMA per K-step per wave.
constexpr int TM = 128, TN = 128, KSPLIT = 8, COLT = K_N / KSPLIT / TN; // 8
constexpr int LDP = 40;   // padded LDS row stride (shorts): 80 B -> ~2-way banks

// load 16 consecutive f32, split into bf16 hi/lo (truncate hi, exact residual,
// truncate lo: residual error ~2^-16 relative), write 2x uint4 to each buffer
__device__ __forceinline__ void stage16(const float* __restrict__ g,
                                        ushort* __restrict__ h,
                                        ushort* __restrict__ l) {
  float v[16];
  *(float4*)&v[0]  = *(const float4*)&g[0];
  *(float4*)&v[4]  = *(const float4*)&g[4];
  *(float4*)&v[8]  = *(const float4*)&g[8];
  *(float4*)&v[12] = *(const float4*)&g[12];
  uint hw[8], lw[8];
  #pragma unroll
  for (int i = 0; i < 8; i++) {
    uint b0 = __float_as_uint(v[2*i]);
    uint b1 = __float_as_uint(v[2*i+1]);
    float r0 = v[2*i]   - __uint_as_float(b0 & 0xFFFF0000u);
    float r1 = v[2*i+1] - __uint_as_float(b1 & 0xFFFF0000u);
    hw[i] = (b0 >> 16) | (b1 & 0xFFFF0000u);
    lw[i] = (__float_as_uint(r0) >> 16) | (__float_as_uint(r1) & 0xFFFF0000u);
  }
  ((uint4*)h)[0] = *(uint4*)&hw[0];
  ((uint4*)h)[1] = *(uint4*)&hw[4];
  ((uint4*)l)[0] = *(uint4*)&lw[0];
  ((uint4*)l)[1] = *(uint4*)&lw[4];
}

__global__ __launch_bounds__(256, 2) void score_argmin_mfma(
    const float* __restrict__ z, const float* __restrict__ w,
    const float* __restrict__ wsq, unsigned long long* __restrict__ packed) {
  __shared__ ushort Ah[TM][LDP];
  __shared__ ushort Al[TM][LDP];
  __shared__ ushort Bh[TN][LDP];
  __shared__ ushort Bl[TN][LDP];

  const int t    = threadIdx.x;
  const int lane = t & 63, wid = t >> 6;
  const int wm   = wid >> 1, wn = wid & 1;      // wave 2x2 grid
  const int l15  = lane & 15, lg = lane >> 4;
  const int row0 = blockIdx.x * TM;
  const int ks0  = blockIdx.y * (K_N / KSPLIT);

  const int srow = t >> 1;            // staging: row 0..127
  const int skq  = (t & 1) * 16;      // staging: k-offset 0/16

  float rmin[16]; int ridx[16];       // running argmin: 16 rows/lane
  #pragma unroll
  for (int e = 0; e < 16; e++) { rmin[e] = 3.4e38f; ridx[e] = 0; }

  for (int ct = 0; ct < COLT; ct++) {
    const int c0 = ks0 + ct * TN;
    f32x4 acc[4][4];
    #pragma unroll
    for (int i = 0; i < 4; i++)
      #pragma unroll
      for (int j = 0; j < 4; j++) acc[i][j] = (f32x4){0.f, 0.f, 0.f, 0.f};

    for (int k0 = 0; k0 < D_N; k0 += 32) {
      __syncthreads();   // previous iteration's readers done
      stage16(&z[(size_t)(row0 + srow) * D_N + k0 + skq], &Ah[srow][skq], &Al[srow][skq]);
      stage16(&w[(size_t)(c0   + srow) * D_N + k0 + skq], &Bh[srow][skq], &Bl[srow][skq]);
      __syncthreads();

      bf16x8 ah[4], al[4], bh[4], bl[4];
      #pragma unroll
      for (int i = 0; i < 4; i++) {
        ah[i] = *(const bf16x8*)&Ah[wm*64 + i*16 + l15][lg*8];
        al[i] = *(const bf16x8*)&Al[wm*64 + i*16 + l15][lg*8];
        bh[i] = *(const bf16x8*)&Bh[wn*64 + i*16 + l15][lg*8];
        bl[i] = *(const bf16x8*)&Bl[wn*64 + i*16 + l15][lg*8];
      }
      #pragma unroll
      for (int i = 0; i < 4; i++)
        #pragma unroll
        for (int j = 0; j < 4; j++) {
          acc[i][j] = __builtin_amdgcn_mfma_f32_16x16x32_bf16(ah[i], bh[j], acc[i][j], 0, 0, 0);
          acc[i][j] = __builtin_amdgcn_mfma_f32_16x16x32_bf16(ah[i], bl[j], acc[i][j], 0, 0, 0);
          acc[i][j] = __builtin_amdgcn_mfma_f32_16x16x32_bf16(al[i], bh[j], acc[i][j], 0, 0, 0);
        }
    }

    // epilogue: dist = wsq[col] - 2*dot; C/D layout col=lane&15, row=(lane>>4)*4+reg
    float wq[4];
    #pragma unroll
    for (int j = 0; j < 4; j++) wq[j] = wsq[c0 + wn*64 + j*16 + l15];
    #pragma unroll
    for (int i = 0; i < 4; i++)
      #pragma unroll
      for (int r = 0; r < 4; r++) {
        const int e = i * 4 + r;
        #pragma unroll
        for (int j = 0; j < 4; j++) {
          float dist = wq[j] - 2.0f * acc[i][j][r];
          if (dist < rmin[e]) { rmin[e] = dist; ridx[e] = c0 + wn*64 + j*16 + l15; }
        }
      }
  }

  // butterfly reduce across the 16 lanes sharing each row (xor 1,2,4,8)
  #pragma unroll
  for (int e = 0; e < 16; e++) {
    float v = rmin[e]; int ix = ridx[e];
    #pragma unroll
    for (int m = 1; m < 16; m <<= 1) {
      float ov = __shfl_xor(v, m, 64);
      int   oi = __shfl_xor(ix, m, 64);
      if (ov < v || (ov == v && oi < ix)) { v = ov; ix = oi; }
    }
    rmin[e] = v; ridx[e] = ix;
  }
  // lane (l15==s) commits entry s: row = wm*64 + (s>>2)*16 + lg*4 + (s&3)
  const int s = l15;
  float bv = 0.f; int bi = 0;
  #pragma unroll
  for (int e = 0; e < 16; e++) {         // static-index select (rule #20)
    bool p = (e == s);
    bv = p ? rmin[e] : bv;
    bi = p ? ridx[e] : bi;
  }
  unsigned u = __float_as_uint(bv);
  u = (u & 0x80000000u) ? ~u : (u | 0x80000000u);
  unsigned long long key = ((unsigned long long)u << 32) | (unsigned)bi;
  atomicMin(&packed[row0 + wm*64 + (s >> 2)*16 + lg*4 + (s & 3)], key);
}

// ------------------------------------------------- gather + loss + scatter -
__global__ __launch_bounds__(256) void gather_scatter(
    const float* __restrict__ z, const float* __restrict__ w,
    const unsigned long long* __restrict__ packed,
    float* __restrict__ qout, float* __restrict__ idxout,
    float* __restrict__ ncs_out, float* __restrict__ nedw_out,
    float* __restrict__ loss_sum) {
  int row = blockIdx.x;
  int t   = threadIdx.x;
  int idx = (int)(packed[row] & 0xFFFFFFFFull);
  float2 zv = *(const float2*)&z[(size_t)row * D_N + t * 2];
  float2 wv = *(const float2*)&w[(size_t)idx * D_N + t * 2];
  float2 q;
  q.x = zv.x + (wv.x - zv.x);
  q.y = zv.y + (wv.y - zv.y);
  *(float2*)&qout[(size_t)row * D_N + t * 2] = q;
  float dx = zv.x - wv.x, dy = zv.y - wv.y;
  float s = dx*dx + dy*dy;
  #pragma unroll
  for (int off = 32; off; off >>= 1) s += __shfl_down(s, off);
  __shared__ float part[4];
  if ((t & 63) == 0) part[t >> 6] = s;
  __syncthreads();
  if (t == 0) {
    atomicAdd(loss_sum, part[0] + part[1] + part[2] + part[3]);
    atomicAdd(&ncs_out[idx], ONE_M_EMA);
    idxout[row] = (float)idx;
  }
  atomicAdd(&nedw_out[(size_t)idx * D_N + t*2],     ONE_M_EMA * zv.x);
  atomicAdd(&nedw_out[(size_t)idx * D_N + t*2 + 1], ONE_M_EMA * zv.y);
}

// ------------------------------------------------------------- reductions -
__global__ __launch_bounds__(256) void reduce_n(const float* __restrict__ ncs_out,
                                                float* __restrict__ nsum) {
  int t = threadIdx.x;
  float s = 0.f;
  for (int i = t; i < K_N; i += 256) s += ncs_out[i];
  #pragma unroll
  for (int off = 32; off; off >>= 1) s += __shfl_down(s, off);
  __shared__ float part[4];
  if ((t & 63) == 0) part[t >> 6] = s;
  __syncthreads();
  if (t == 0) nsum[0] = part[0] + part[1] + part[2] + part[3];
}

__global__ __launch_bounds__(256) void finalize(
    const float* __restrict__ ncs_out, const float* __restrict__ nedw_out,
    float* __restrict__ nw_out, const float* __restrict__ nsum,
    const float* __restrict__ loss_sum, float* __restrict__ loss_out) {
  size_t i = (size_t)blockIdx.x * 256 + threadIdx.x;
  float n = nsum[0];
  int k = (int)(i >> 9);
  float nv = ncs_out[k];
  float cs = (nv + EPS_) / (n + K_N * EPS_) * n;
  nw_out[i] = nedw_out[i] / cs;
  if (i == 0) loss_out[0] = CCOST * loss_sum[0] / (float)((size_t)B_N * D_N);
}

// ------------------------------------------------------------------ launch -
extern "C" void kernel_launch(void* const* d_in, const int* in_sizes, int n_in,
                              void* d_out, int out_size, void* d_ws, size_t ws_size,
                              hipStream_t stream) {
  const float* z   = (const float*)d_in[0];
  const float* w   = (const float*)d_in[1];
  const float* ecs = (const float*)d_in[2];
  const float* edw = (const float*)d_in[3];

  float* out      = (float*)d_out;
  float* qout     = out;
  float* idxout   = out + (size_t)B_N * D_N;
  float* loss_out = idxout + B_N;
  float* nw_out   = loss_out + 1;
  float* ncs_out  = nw_out + (size_t)K_N * D_N;
  float* nedw_out = ncs_out + K_N;

  unsigned long long* packed = (unsigned long long*)d_ws;
  float* wsq      = (float*)((char*)d_ws + 262144);
  float* loss_sum = (float*)((char*)d_ws + 294912);
  float* nsum     = loss_sum + 1;

  hipMemsetAsync(d_ws, 0xFF, 262144, stream);
  hipMemsetAsync((void*)loss_sum, 0, 8, stream);

  prep_kernel<<<2048, 256, 0, stream>>>(w, ecs, wsq, ncs_out);
  prep_nedw<<<4096, 256, 0, stream>>>((const float4*)edw, (float4*)nedw_out);
  score_argmin_mfma<<<dim3(B_N / TM, KSPLIT), 256, 0, stream>>>(z, w, wsq, packed);
  gather_scatter<<<B_N, 256, 0, stream>>>(z, w, packed, qout, idxout,
                                          ncs_out, nedw_out, loss_sum);
  reduce_n<<<1, 256, 0, stream>>>(ncs_out, nsum);
  finalize<<<K_N * D_N / 256, 256, 0, stream>>>(ncs_out, nedw_out, nw_out,
                                                nsum, loss_sum, loss_out);
}

// Round 3
// 1421.085 us; speedup vs baseline: 2.7271x; 1.0554x over previous
//
#include <hip/hip_runtime.h>

#define B_N 32768
#define D_N 512
#define K_N 8192
#define EMA 0.99f
#define ONE_M_EMA 0.01f
#define EPS_ 1e-5f
#define CCOST 0.25f

// ws layout (fast path):
// [0, 262144)            : u64 packed[B_N]  (sortable_dist<<32 | idx), init 0xFF
// [262144, 294912)       : float wsq[K_N]
// [294912, 294920)       : float loss_sum, n_sum
// [295936, +100663296)   : ushort zp[32768][1536]  packed bf16 [zh|zh|zl], swizzled
// [100959232, +25165824) : ushort wp[8192][1536]   packed bf16 [wh|wl|wh], swizzled
#define ZP_OFF 295936ull
#define WP_OFF 100959232ull
#define WS_NEED (WP_OFF + 25165824ull)

typedef __attribute__((ext_vector_type(8))) short bf16x8;
typedef __attribute__((ext_vector_type(4))) float f32x4;

// ---------------------------------------------------------------- prep ----
__global__ __launch_bounds__(256) void prep_kernel(const float* __restrict__ w,
                                                   const float* __restrict__ ecs,
                                                   float* __restrict__ wsq,
                                                   float* __restrict__ ncs_out) {
  int row  = blockIdx.x * 4 + (threadIdx.x >> 6);
  int lane = threadIdx.x & 63;
  const float* p = w + (size_t)row * D_N + lane * 8;
  float4 a = *(const float4*)p;
  float4 b = *(const float4*)(p + 4);
  float s = a.x*a.x + a.y*a.y + a.z*a.z + a.w*a.w
          + b.x*b.x + b.y*b.y + b.z*b.z + b.w*b.w;
  #pragma unroll
  for (int off = 32; off; off >>= 1) s += __shfl_down(s, off);
  if (lane == 0) wsq[row] = s;

  int gid = blockIdx.x * 256 + threadIdx.x;
  if (gid < K_N) ncs_out[gid] = EMA * ecs[gid];
}

__global__ __launch_bounds__(256) void prep_nedw(const float4* __restrict__ edw,
                                                 float4* __restrict__ nedw) {
  int i = blockIdx.x * 256 + threadIdx.x;
  float4 v = edw[i];
  v.x *= EMA; v.y *= EMA; v.z *= EMA; v.w *= EMA;
  nedw[i] = v;
}

// ------------------------------------------------------------ pre-split ---
// x[R][512] f32 -> xp[R][1536] bf16, three K-sections; hi = truncate(x),
// lo = truncate(x - hi).  mode 0 (z): [hi|hi|lo]; mode 1 (w): [hi|lo|hi].
// Within each 128B k-slice, 16B chunks stored at position (c ^ (row&7)):
// the T2 swizzle baked into the layout so global_load_lds stays linear.
__global__ __launch_bounds__(256) void split_pack(const float* __restrict__ x,
                                                  ushort* __restrict__ xp,
                                                  int mode) {
  int g   = blockIdx.x * 256 + threadIdx.x;
  int row = g >> 6, c = g & 63;            // c: source 8-elem chunk in row
  const float* src = x + (size_t)row * 512 + c * 8;
  float v[8];
  *(float4*)&v[0] = *(const float4*)&src[0];
  *(float4*)&v[4] = *(const float4*)&src[4];
  uint hw[4], lw[4];
  #pragma unroll
  for (int i = 0; i < 4; i++) {
    uint b0 = __float_as_uint(v[2*i]);
    uint b1 = __float_as_uint(v[2*i+1]);
    float r0 = v[2*i]   - __uint_as_float(b0 & 0xFFFF0000u);
    float r1 = v[2*i+1] - __uint_as_float(b1 & 0xFFFF0000u);
    hw[i] = (b0 >> 16) | (b1 & 0xFFFF0000u);
    lw[i] = (__float_as_uint(r0) >> 16) | (__float_as_uint(r1) & 0xFFFF0000u);
  }
  uint4 H = {hw[0], hw[1], hw[2], hw[3]};
  uint4 L = {lw[0], lw[1], lw[2], lw[3]};
  size_t rb = (size_t)row * 1536;
  int ksl_in = c >> 3;                      // slice within section (0..7)
  int sw = ((c & 7) ^ (row & 7)) * 8;       // swizzled bf16 offset in slice
  size_t d0 = rb + (size_t)(0 * 8 + ksl_in) * 64 + sw;
  size_t d1 = rb + (size_t)(1 * 8 + ksl_in) * 64 + sw;
  size_t d2 = rb + (size_t)(2 * 8 + ksl_in) * 64 + sw;
  if (mode == 0) {           // z: [hi|hi|lo]
    *(uint4*)&xp[d0] = H; *(uint4*)&xp[d1] = H; *(uint4*)&xp[d2] = L;
  } else {                   // w: [hi|lo|hi]
    *(uint4*)&xp[d0] = H; *(uint4*)&xp[d1] = L; *(uint4*)&xp[d2] = H;
  }
}

// --------------------------------------------------------- score+argmin ---
// dist'[b,k] = wsq[k] - 2 * z[b]·w[k]; dot via K'=1536 bf16 GEMM (3-term).
// 128x128 tile, BK=64, 4 waves (2x2 of 64x64), dbuf LDS, global_load_lds.
constexpr int KSPLIT = 8, COLT = K_N / KSPLIT / 128;   // 8 col-tiles/block

__global__ __launch_bounds__(256, 2) void score3(
    const ushort* __restrict__ zp, const ushort* __restrict__ wp,
    const float* __restrict__ wsq, unsigned long long* __restrict__ packed) {
  __shared__ ushort As[2][128 * 64];
  __shared__ ushort Bs[2][128 * 64];

  const int t = threadIdx.x, lane = t & 63, wid = t >> 6;
  const int wm = wid >> 1, wn = wid & 1;
  const int l15 = lane & 15, lg = lane >> 4;
  const int row0 = blockIdx.x * 128;
  const int ks0  = blockIdx.y * (K_N / KSPLIT);

  // staging: issue q covers rows [q*32, q*32+32); wave wid stages its 8 rows
  const int srow   = wid * 8 + (lane >> 3);
  const int schunk = lane & 7;
  const char* zsb = (const char*)zp + (size_t)(row0 + srow) * 3072 + schunk * 16;

  // ds_read offsets (ushort units), constant across the K loop
  const int xm = l15 & 7;
  int aoff[4][2], boff[4][2];
  #pragma unroll
  for (int i = 0; i < 4; i++)
    #pragma unroll
    for (int kk = 0; kk < 2; kk++) {
      aoff[i][kk] = (wm * 64 + i * 16 + l15) * 64 + (((kk * 4 + lg) ^ xm) * 8);
      boff[i][kk] = (wn * 64 + i * 16 + l15) * 64 + (((kk * 4 + lg) ^ xm) * 8);
    }

  float rmin[16]; int ridx[16];
  #pragma unroll
  for (int e = 0; e < 16; e++) { rmin[e] = 3.4e38f; ridx[e] = 0; }

  for (int ct = 0; ct < COLT; ct++) {
    const int c0 = ks0 + ct * 128;
    const char* wsb = (const char*)wp + (size_t)(c0 + srow) * 3072 + schunk * 16;

    f32x4 acc[4][4];
    #pragma unroll
    for (int i = 0; i < 4; i++)
      #pragma unroll
      for (int j = 0; j < 4; j++) acc[i][j] = (f32x4){0.f, 0.f, 0.f, 0.f};

    // prologue: stage slice 0 into buf 0
    #pragma unroll
    for (int q = 0; q < 4; q++) {
      __builtin_amdgcn_global_load_lds((const unsigned int*)(zsb + q * 98304),
                                       (unsigned int*)&As[0][q * 2048 + wid * 512], 16, 0, 0);
      __builtin_amdgcn_global_load_lds((const unsigned int*)(wsb + q * 98304),
                                       (unsigned int*)&Bs[0][q * 2048 + wid * 512], 16, 0, 0);
    }
    __syncthreads();                       // drains vmcnt -> buf0 ready

    for (int s = 0; s < 24; s++) {
      const int cur = s & 1;
      if (s < 23) {                        // prefetch next slice into buf^1
        const int nxt = cur ^ 1;
        const size_t so = (size_t)(s + 1) * 128;
        #pragma unroll
        for (int q = 0; q < 4; q++) {
          __builtin_amdgcn_global_load_lds((const unsigned int*)(zsb + q * 98304 + so),
                                           (unsigned int*)&As[nxt][q * 2048 + wid * 512], 16, 0, 0);
          __builtin_amdgcn_global_load_lds((const unsigned int*)(wsb + q * 98304 + so),
                                           (unsigned int*)&Bs[nxt][q * 2048 + wid * 512], 16, 0, 0);
        }
      }
      #pragma unroll
      for (int kk = 0; kk < 2; kk++) {
        bf16x8 a[4], b[4];
        #pragma unroll
        for (int i = 0; i < 4; i++) {
          a[i] = *(const bf16x8*)&As[cur][aoff[i][kk]];
          b[i] = *(const bf16x8*)&Bs[cur][boff[i][kk]];
        }
        #pragma unroll
        for (int i = 0; i < 4; i++)
          #pragma unroll
          for (int j = 0; j < 4; j++)
            acc[i][j] = __builtin_amdgcn_mfma_f32_16x16x32_bf16(a[i], b[j], acc[i][j], 0, 0, 0);
      }
      __syncthreads();                     // next buf staged + readers done
    }

    // epilogue: dist = wsq[col] - 2*dot; C/D: col=lane&15, row=(lane>>4)*4+reg
    float wq[4];
    #pragma unroll
    for (int j = 0; j < 4; j++) wq[j] = wsq[c0 + wn * 64 + j * 16 + l15];
    #pragma unroll
    for (int i = 0; i < 4; i++)
      #pragma unroll
      for (int r = 0; r < 4; r++) {
        const int e = i * 4 + r;
        #pragma unroll
        for (int j = 0; j < 4; j++) {
          float dist = wq[j] - 2.0f * acc[i][j][r];
          if (dist < rmin[e]) { rmin[e] = dist; ridx[e] = c0 + wn * 64 + j * 16 + l15; }
        }
      }
  }

  // butterfly reduce across the 16 lanes sharing each row
  #pragma unroll
  for (int e = 0; e < 16; e++) {
    float v = rmin[e]; int ix = ridx[e];
    #pragma unroll
    for (int m = 1; m < 16; m <<= 1) {
      float ov = __shfl_xor(v, m, 64);
      int   oi = __shfl_xor(ix, m, 64);
      if (ov < v || (ov == v && oi < ix)) { v = ov; ix = oi; }
    }
    rmin[e] = v; ridx[e] = ix;
  }
  const int s = l15;
  float bv = 0.f; int bi = 0;
  #pragma unroll
  for (int e = 0; e < 16; e++) {           // static-index select (rule #20)
    bool p = (e == s);
    bv = p ? rmin[e] : bv;
    bi = p ? ridx[e] : bi;
  }
  unsigned u = __float_as_uint(bv);
  u = (u & 0x80000000u) ? ~u : (u | 0x80000000u);
  unsigned long long key = ((unsigned long long)u << 32) | (unsigned)bi;
  atomicMin(&packed[row0 + wm * 64 + (s >> 2) * 16 + lg * 4 + (s & 3)], key);
}

// ---------------------------------------- fallback score (round-2 kernel) --
constexpr int LDP = 40;
__device__ __forceinline__ void stage16(const float* __restrict__ g,
                                        ushort* __restrict__ h,
                                        ushort* __restrict__ l) {
  float v[16];
  *(float4*)&v[0]  = *(const float4*)&g[0];
  *(float4*)&v[4]  = *(const float4*)&g[4];
  *(float4*)&v[8]  = *(const float4*)&g[8];
  *(float4*)&v[12] = *(const float4*)&g[12];
  uint hw[8], lw[8];
  #pragma unroll
  for (int i = 0; i < 8; i++) {
    uint b0 = __float_as_uint(v[2*i]);
    uint b1 = __float_as_uint(v[2*i+1]);
    float r0 = v[2*i]   - __uint_as_float(b0 & 0xFFFF0000u);
    float r1 = v[2*i+1] - __uint_as_float(b1 & 0xFFFF0000u);
    hw[i] = (b0 >> 16) | (b1 & 0xFFFF0000u);
    lw[i] = (__float_as_uint(r0) >> 16) | (__float_as_uint(r1) & 0xFFFF0000u);
  }
  ((uint4*)h)[0] = *(uint4*)&hw[0];
  ((uint4*)h)[1] = *(uint4*)&hw[4];
  ((uint4*)l)[0] = *(uint4*)&lw[0];
  ((uint4*)l)[1] = *(uint4*)&lw[4];
}

__global__ __launch_bounds__(256, 2) void score_argmin_mfma(
    const float* __restrict__ z, const float* __restrict__ w,
    const float* __restrict__ wsq, unsigned long long* __restrict__ packed) {
  __shared__ ushort Ah[128][LDP];
  __shared__ ushort Al[128][LDP];
  __shared__ ushort Bh[128][LDP];
  __shared__ ushort Bl[128][LDP];
  const int t = threadIdx.x, lane = t & 63, wid = t >> 6;
  const int wm = wid >> 1, wn = wid & 1;
  const int l15 = lane & 15, lg = lane >> 4;
  const int row0 = blockIdx.x * 128;
  const int ks0  = blockIdx.y * (K_N / KSPLIT);
  const int srow = t >> 1, skq = (t & 1) * 16;
  float rmin[16]; int ridx[16];
  #pragma unroll
  for (int e = 0; e < 16; e++) { rmin[e] = 3.4e38f; ridx[e] = 0; }
  for (int ct = 0; ct < COLT; ct++) {
    const int c0 = ks0 + ct * 128;
    f32x4 acc[4][4];
    #pragma unroll
    for (int i = 0; i < 4; i++)
      #pragma unroll
      for (int j = 0; j < 4; j++) acc[i][j] = (f32x4){0.f, 0.f, 0.f, 0.f};
    for (int k0 = 0; k0 < D_N; k0 += 32) {
      __syncthreads();
      stage16(&z[(size_t)(row0 + srow) * D_N + k0 + skq], &Ah[srow][skq], &Al[srow][skq]);
      stage16(&w[(size_t)(c0   + srow) * D_N + k0 + skq], &Bh[srow][skq], &Bl[srow][skq]);
      __syncthreads();
      bf16x8 ah[4], al[4], bh[4], bl[4];
      #pragma unroll
      for (int i = 0; i < 4; i++) {
        ah[i] = *(const bf16x8*)&Ah[wm*64 + i*16 + l15][lg*8];
        al[i] = *(const bf16x8*)&Al[wm*64 + i*16 + l15][lg*8];
        bh[i] = *(const bf16x8*)&Bh[wn*64 + i*16 + l15][lg*8];
        bl[i] = *(const bf16x8*)&Bl[wn*64 + i*16 + l15][lg*8];
      }
      #pragma unroll
      for (int i = 0; i < 4; i++)
        #pragma unroll
        for (int j = 0; j < 4; j++) {
          acc[i][j] = __builtin_amdgcn_mfma_f32_16x16x32_bf16(ah[i], bh[j], acc[i][j], 0, 0, 0);
          acc[i][j] = __builtin_amdgcn_mfma_f32_16x16x32_bf16(ah[i], bl[j], acc[i][j], 0, 0, 0);
          acc[i][j] = __builtin_amdgcn_mfma_f32_16x16x32_bf16(al[i], bh[j], acc[i][j], 0, 0, 0);
        }
    }
    float wq[4];
    #pragma unroll
    for (int j = 0; j < 4; j++) wq[j] = wsq[c0 + wn*64 + j*16 + l15];
    #pragma unroll
    for (int i = 0; i < 4; i++)
      #pragma unroll
      for (int r = 0; r < 4; r++) {
        const int e = i * 4 + r;
        #pragma unroll
        for (int j = 0; j < 4; j++) {
          float dist = wq[j] - 2.0f * acc[i][j][r];
          if (dist < rmin[e]) { rmin[e] = dist; ridx[e] = c0 + wn*64 + j*16 + l15; }
        }
      }
  }
  #pragma unroll
  for (int e = 0; e < 16; e++) {
    float v = rmin[e]; int ix = ridx[e];
    #pragma unroll
    for (int m = 1; m < 16; m <<= 1) {
      float ov = __shfl_xor(v, m, 64);
      int   oi = __shfl_xor(ix, m, 64);
      if (ov < v || (ov == v && oi < ix)) { v = ov; ix = oi; }
    }
    rmin[e] = v; ridx[e] = ix;
  }
  const int s = l15;
  float bv = 0.f; int bi = 0;
  #pragma unroll
  for (int e = 0; e < 16; e++) {
    bool p = (e == s);
    bv = p ? rmin[e] : bv;
    bi = p ? ridx[e] : bi;
  }
  unsigned u = __float_as_uint(bv);
  u = (u & 0x80000000u) ? ~u : (u | 0x80000000u);
  unsigned long long key = ((unsigned long long)u << 32) | (unsigned)bi;
  atomicMin(&packed[row0 + wm*64 + (s >> 2)*16 + lg*4 + (s & 3)], key);
}

// ------------------------------------------------- gather + loss + scatter -
__global__ __launch_bounds__(256) void gather_scatter(
    const float* __restrict__ z, const float* __restrict__ w,
    const unsigned long long* __restrict__ packed,
    float* __restrict__ qout, float* __restrict__ idxout,
    float* __restrict__ ncs_out, float* __restrict__ nedw_out,
    float* __restrict__ loss_sum) {
  int row = blockIdx.x;
  int t   = threadIdx.x;
  int idx = (int)(packed[row] & 0xFFFFFFFFull);
  float2 zv = *(const float2*)&z[(size_t)row * D_N + t * 2];
  float2 wv = *(const float2*)&w[(size_t)idx * D_N + t * 2];
  float2 q;
  q.x = zv.x + (wv.x - zv.x);
  q.y = zv.y + (wv.y - zv.y);
  *(float2*)&qout[(size_t)row * D_N + t * 2] = q;
  float dx = zv.x - wv.x, dy = zv.y - wv.y;
  float s = dx*dx + dy*dy;
  #pragma unroll
  for (int off = 32; off; off >>= 1) s += __shfl_down(s, off);
  __shared__ float part[4];
  if ((t & 63) == 0) part[t >> 6] = s;
  __syncthreads();
  if (t == 0) {
    atomicAdd(loss_sum, part[0] + part[1] + part[2] + part[3]);
    atomicAdd(&ncs_out[idx], ONE_M_EMA);
    idxout[row] = (float)idx;
  }
  atomicAdd(&nedw_out[(size_t)idx * D_N + t*2],     ONE_M_EMA * zv.x);
  atomicAdd(&nedw_out[(size_t)idx * D_N + t*2 + 1], ONE_M_EMA * zv.y);
}

// ------------------------------------------------------------- reductions -
__global__ __launch_bounds__(256) void reduce_n(const float* __restrict__ ncs_out,
                                                float* __restrict__ nsum) {
  int t = threadIdx.x;
  float s = 0.f;
  for (int i = t; i < K_N; i += 256) s += ncs_out[i];
  #pragma unroll
  for (int off = 32; off; off >>= 1) s += __shfl_down(s, off);
  __shared__ float part[4];
  if ((t & 63) == 0) part[t >> 6] = s;
  __syncthreads();
  if (t == 0) nsum[0] = part[0] + part[1] + part[2] + part[3];
}

__global__ __launch_bounds__(256) void finalize(
    const float* __restrict__ ncs_out, const float* __restrict__ nedw_out,
    float* __restrict__ nw_out, const float* __restrict__ nsum,
    const float* __restrict__ loss_sum, float* __restrict__ loss_out) {
  size_t i = (size_t)blockIdx.x * 256 + threadIdx.x;
  float n = nsum[0];
  int k = (int)(i >> 9);
  float nv = ncs_out[k];
  float cs = (nv + EPS_) / (n + K_N * EPS_) * n;
  nw_out[i] = nedw_out[i] / cs;
  if (i == 0) loss_out[0] = CCOST * loss_sum[0] / (float)((size_t)B_N * D_N);
}

// ------------------------------------------------------------------ launch -
extern "C" void kernel_launch(void* const* d_in, const int* in_sizes, int n_in,
                              void* d_out, int out_size, void* d_ws, size_t ws_size,
                              hipStream_t stream) {
  const float* z   = (const float*)d_in[0];
  const float* w   = (const float*)d_in[1];
  const float* ecs = (const float*)d_in[2];
  const float* edw = (const float*)d_in[3];

  float* out      = (float*)d_out;
  float* qout     = out;
  float* idxout   = out + (size_t)B_N * D_N;
  float* loss_out = idxout + B_N;
  float* nw_out   = loss_out + 1;
  float* ncs_out  = nw_out + (size_t)K_N * D_N;
  float* nedw_out = ncs_out + K_N;

  unsigned long long* packed = (unsigned long long*)d_ws;
  float* wsq      = (float*)((char*)d_ws + 262144);
  float* loss_sum = (float*)((char*)d_ws + 294912);
  float* nsum     = loss_sum + 1;

  hipMemsetAsync(d_ws, 0xFF, 262144, stream);
  hipMemsetAsync((void*)loss_sum, 0, 8, stream);

  prep_kernel<<<2048, 256, 0, stream>>>(w, ecs, wsq, ncs_out);
  prep_nedw<<<4096, 256, 0, stream>>>((const float4*)edw, (float4*)nedw_out);

  if (ws_size >= WS_NEED) {
    ushort* zp = (ushort*)((char*)d_ws + ZP_OFF);
    ushort* wp = (ushort*)((char*)d_ws + WP_OFF);
    split_pack<<<8192, 256, 0, stream>>>(z, zp, 0);
    split_pack<<<2048, 256, 0, stream>>>(w, wp, 1);
    score3<<<dim3(B_N / 128, KSPLIT), 256, 0, stream>>>(zp, wp, wsq, packed);
  } else {
    score_argmin_mfma<<<dim3(B_N / 128, KSPLIT), 256, 0, stream>>>(z, w, wsq, packed);
  }

  gather_scatter<<<B_N, 256, 0, stream>>>(z, w, packed, qout, idxout,
                                          ncs_out, nedw_out, loss_sum);
  reduce_n<<<1, 256, 0, stream>>>(ncs_out, nsum);
  finalize<<<K_N * D_N / 256, 256, 0, stream>>>(ncs_out, nedw_out, nw_out,
                                                nsum, loss_sum, loss_out);
}

// Round 4
// 1148.007 us; speedup vs baseline: 3.3758x; 1.2379x over previous
//
#include <hip/hip_runtime.h>

#define B_N 32768
#define D_N 512
#define K_N 8192
#define EMA 0.99f
#define ONE_M_EMA 0.01f
#define EPS_ 1e-5f
#define CCOST 0.25f

// ws layout (fast path):
// [0, 262144)            : u64 packed[B_N]  (sortable_dist<<32 | idx), init 0xFF
// [262144, 294912)       : float wsq[K_N]
// [294912, 294920)       : float loss_sum, n_sum
// [295936, +100663296)   : ushort zp[32768][1536]  packed bf16 [zh|zh|zl], swizzled
// [100959232, +25165824) : ushort wp[8192][1536]   packed bf16 [wh|wl|wh], swizzled
// AUX (aliases zp region, used only AFTER score3):
//   cnt[8192] i32 @ +295936, offs[8193] i32 @ +332800, cursor[8192] i32 @ +365568,
//   rowlist[32768] i32 @ +398336, lpart[32768] f32 @ +529408
#define ZP_OFF 295936ull
#define WP_OFF 100959232ull
#define WS_NEED (WP_OFF + 25165824ull)
#define CNT_OFF    295936ull
#define OFFS_OFF   332800ull
#define CURS_OFF   365568ull
#define ROWL_OFF   398336ull
#define LPART_OFF  529408ull

typedef __attribute__((ext_vector_type(8))) short bf16x8;
typedef __attribute__((ext_vector_type(4))) float f32x4;

// ---------------------------------------------------------------- prep ----
__global__ __launch_bounds__(256) void prep_kernel(const float* __restrict__ w,
                                                   const float* __restrict__ ecs,
                                                   float* __restrict__ wsq,
                                                   float* __restrict__ ncs_out) {
  int row  = blockIdx.x * 4 + (threadIdx.x >> 6);
  int lane = threadIdx.x & 63;
  const float* p = w + (size_t)row * D_N + lane * 8;
  float4 a = *(const float4*)p;
  float4 b = *(const float4*)(p + 4);
  float s = a.x*a.x + a.y*a.y + a.z*a.z + a.w*a.w
          + b.x*b.x + b.y*b.y + b.z*b.z + b.w*b.w;
  #pragma unroll
  for (int off = 32; off; off >>= 1) s += __shfl_down(s, off);
  if (lane == 0) wsq[row] = s;

  int gid = blockIdx.x * 256 + threadIdx.x;           // fallback-path ncs init
  if (gid < K_N) ncs_out[gid] = EMA * ecs[gid];
}

__global__ __launch_bounds__(256) void prep_nedw(const float4* __restrict__ edw,
                                                 float4* __restrict__ nedw) {
  int i = blockIdx.x * 256 + threadIdx.x;
  float4 v = edw[i];
  v.x *= EMA; v.y *= EMA; v.z *= EMA; v.w *= EMA;
  nedw[i] = v;
}

// ------------------------------------------------------------ pre-split ---
__global__ __launch_bounds__(256) void split_pack(const float* __restrict__ x,
                                                  ushort* __restrict__ xp,
                                                  int mode) {
  int g   = blockIdx.x * 256 + threadIdx.x;
  int row = g >> 6, c = g & 63;
  const float* src = x + (size_t)row * 512 + c * 8;
  float v[8];
  *(float4*)&v[0] = *(const float4*)&src[0];
  *(float4*)&v[4] = *(const float4*)&src[4];
  uint hw[4], lw[4];
  #pragma unroll
  for (int i = 0; i < 4; i++) {
    uint b0 = __float_as_uint(v[2*i]);
    uint b1 = __float_as_uint(v[2*i+1]);
    float r0 = v[2*i]   - __uint_as_float(b0 & 0xFFFF0000u);
    float r1 = v[2*i+1] - __uint_as_float(b1 & 0xFFFF0000u);
    hw[i] = (b0 >> 16) | (b1 & 0xFFFF0000u);
    lw[i] = (__float_as_uint(r0) >> 16) | (__float_as_uint(r1) & 0xFFFF0000u);
  }
  uint4 H = {hw[0], hw[1], hw[2], hw[3]};
  uint4 L = {lw[0], lw[1], lw[2], lw[3]};
  size_t rb = (size_t)row * 1536;
  int ksl_in = c >> 3;
  int sw = ((c & 7) ^ (row & 7)) * 8;
  size_t d0 = rb + (size_t)(0 * 8 + ksl_in) * 64 + sw;
  size_t d1 = rb + (size_t)(1 * 8 + ksl_in) * 64 + sw;
  size_t d2 = rb + (size_t)(2 * 8 + ksl_in) * 64 + sw;
  if (mode == 0) {           // z: [hi|hi|lo]
    *(uint4*)&xp[d0] = H; *(uint4*)&xp[d1] = H; *(uint4*)&xp[d2] = L;
  } else {                   // w: [hi|lo|hi]
    *(uint4*)&xp[d0] = H; *(uint4*)&xp[d1] = L; *(uint4*)&xp[d2] = H;
  }
}

// --------------------------------------------------------- score+argmin ---
constexpr int KSPLIT = 8, COLT = K_N / KSPLIT / 128;

__global__ __launch_bounds__(256, 2) void score3(
    const ushort* __restrict__ zp, const ushort* __restrict__ wp,
    const float* __restrict__ wsq, unsigned long long* __restrict__ packed) {
  __shared__ ushort As[2][128 * 64];
  __shared__ ushort Bs[2][128 * 64];

  const int t = threadIdx.x, lane = t & 63, wid = t >> 6;
  const int wm = wid >> 1, wn = wid & 1;
  const int l15 = lane & 15, lg = lane >> 4;
  const int row0 = blockIdx.x * 128;
  const int ks0  = blockIdx.y * (K_N / KSPLIT);

  const int srow   = wid * 8 + (lane >> 3);
  const int schunk = lane & 7;
  const char* zsb = (const char*)zp + (size_t)(row0 + srow) * 3072 + schunk * 16;

  const int xm = l15 & 7;
  int aoff[4][2], boff[4][2];
  #pragma unroll
  for (int i = 0; i < 4; i++)
    #pragma unroll
    for (int kk = 0; kk < 2; kk++) {
      aoff[i][kk] = (wm * 64 + i * 16 + l15) * 64 + (((kk * 4 + lg) ^ xm) * 8);
      boff[i][kk] = (wn * 64 + i * 16 + l15) * 64 + (((kk * 4 + lg) ^ xm) * 8);
    }

  float rmin[16]; int ridx[16];
  #pragma unroll
  for (int e = 0; e < 16; e++) { rmin[e] = 3.4e38f; ridx[e] = 0; }

  for (int ct = 0; ct < COLT; ct++) {
    const int c0 = ks0 + ct * 128;
    const char* wsb = (const char*)wp + (size_t)(c0 + srow) * 3072 + schunk * 16;

    f32x4 acc[4][4];
    #pragma unroll
    for (int i = 0; i < 4; i++)
      #pragma unroll
      for (int j = 0; j < 4; j++) acc[i][j] = (f32x4){0.f, 0.f, 0.f, 0.f};

    #pragma unroll
    for (int q = 0; q < 4; q++) {
      __builtin_amdgcn_global_load_lds((const unsigned int*)(zsb + q * 98304),
                                       (unsigned int*)&As[0][q * 2048 + wid * 512], 16, 0, 0);
      __builtin_amdgcn_global_load_lds((const unsigned int*)(wsb + q * 98304),
                                       (unsigned int*)&Bs[0][q * 2048 + wid * 512], 16, 0, 0);
    }
    __syncthreads();

    for (int s = 0; s < 24; s++) {
      const int cur = s & 1;
      if (s < 23) {
        const int nxt = cur ^ 1;
        const size_t so = (size_t)(s + 1) * 128;
        #pragma unroll
        for (int q = 0; q < 4; q++) {
          __builtin_amdgcn_global_load_lds((const unsigned int*)(zsb + q * 98304 + so),
                                           (unsigned int*)&As[nxt][q * 2048 + wid * 512], 16, 0, 0);
          __builtin_amdgcn_global_load_lds((const unsigned int*)(wsb + q * 98304 + so),
                                           (unsigned int*)&Bs[nxt][q * 2048 + wid * 512], 16, 0, 0);
        }
      }
      #pragma unroll
      for (int kk = 0; kk < 2; kk++) {
        bf16x8 a[4], b[4];
        #pragma unroll
        for (int i = 0; i < 4; i++) {
          a[i] = *(const bf16x8*)&As[cur][aoff[i][kk]];
          b[i] = *(const bf16x8*)&Bs[cur][boff[i][kk]];
        }
        #pragma unroll
        for (int i = 0; i < 4; i++)
          #pragma unroll
          for (int j = 0; j < 4; j++)
            acc[i][j] = __builtin_amdgcn_mfma_f32_16x16x32_bf16(a[i], b[j], acc[i][j], 0, 0, 0);
      }
      __syncthreads();
    }

    float wq[4];
    #pragma unroll
    for (int j = 0; j < 4; j++) wq[j] = wsq[c0 + wn * 64 + j * 16 + l15];
    #pragma unroll
    for (int i = 0; i < 4; i++)
      #pragma unroll
      for (int r = 0; r < 4; r++) {
        const int e = i * 4 + r;
        #pragma unroll
        for (int j = 0; j < 4; j++) {
          float dist = wq[j] - 2.0f * acc[i][j][r];
          if (dist < rmin[e]) { rmin[e] = dist; ridx[e] = c0 + wn * 64 + j * 16 + l15; }
        }
      }
  }

  #pragma unroll
  for (int e = 0; e < 16; e++) {
    float v = rmin[e]; int ix = ridx[e];
    #pragma unroll
    for (int m = 1; m < 16; m <<= 1) {
      float ov = __shfl_xor(v, m, 64);
      int   oi = __shfl_xor(ix, m, 64);
      if (ov < v || (ov == v && oi < ix)) { v = ov; ix = oi; }
    }
    rmin[e] = v; ridx[e] = ix;
  }
  const int s = l15;
  float bv = 0.f; int bi = 0;
  #pragma unroll
  for (int e = 0; e < 16; e++) {
    bool p = (e == s);
    bv = p ? rmin[e] : bv;
    bi = p ? ridx[e] : bi;
  }
  unsigned u = __float_as_uint(bv);
  u = (u & 0x80000000u) ? ~u : (u | 0x80000000u);
  unsigned long long key = ((unsigned long long)u << 32) | (unsigned)bi;
  atomicMin(&packed[row0 + wm * 64 + (s >> 2) * 16 + lg * 4 + (s & 3)], key);
}

// ---------------------------------------- fallback score (round-2 kernel) --
constexpr int LDP = 40;
__device__ __forceinline__ void stage16(const float* __restrict__ g,
                                        ushort* __restrict__ h,
                                        ushort* __restrict__ l) {
  float v[16];
  *(float4*)&v[0]  = *(const float4*)&g[0];
  *(float4*)&v[4]  = *(const float4*)&g[4];
  *(float4*)&v[8]  = *(const float4*)&g[8];
  *(float4*)&v[12] = *(const float4*)&g[12];
  uint hw[8], lw[8];
  #pragma unroll
  for (int i = 0; i < 8; i++) {
    uint b0 = __float_as_uint(v[2*i]);
    uint b1 = __float_as_uint(v[2*i+1]);
    float r0 = v[2*i]   - __uint_as_float(b0 & 0xFFFF0000u);
    float r1 = v[2*i+1] - __uint_as_float(b1 & 0xFFFF0000u);
    hw[i] = (b0 >> 16) | (b1 & 0xFFFF0000u);
    lw[i] = (__float_as_uint(r0) >> 16) | (__float_as_uint(r1) & 0xFFFF0000u);
  }
  ((uint4*)h)[0] = *(uint4*)&hw[0];
  ((uint4*)h)[1] = *(uint4*)&hw[4];
  ((uint4*)l)[0] = *(uint4*)&lw[0];
  ((uint4*)l)[1] = *(uint4*)&lw[4];
}

__global__ __launch_bounds__(256, 2) void score_argmin_mfma(
    const float* __restrict__ z, const float* __restrict__ w,
    const float* __restrict__ wsq, unsigned long long* __restrict__ packed) {
  __shared__ ushort Ah[128][LDP];
  __shared__ ushort Al[128][LDP];
  __shared__ ushort Bh[128][LDP];
  __shared__ ushort Bl[128][LDP];
  const int t = threadIdx.x, lane = t & 63, wid = t >> 6;
  const int wm = wid >> 1, wn = wid & 1;
  const int l15 = lane & 15, lg = lane >> 4;
  const int row0 = blockIdx.x * 128;
  const int ks0  = blockIdx.y * (K_N / KSPLIT);
  const int srow = t >> 1, skq = (t & 1) * 16;
  float rmin[16]; int ridx[16];
  #pragma unroll
  for (int e = 0; e < 16; e++) { rmin[e] = 3.4e38f; ridx[e] = 0; }
  for (int ct = 0; ct < COLT; ct++) {
    const int c0 = ks0 + ct * 128;
    f32x4 acc[4][4];
    #pragma unroll
    for (int i = 0; i < 4; i++)
      #pragma unroll
      for (int j = 0; j < 4; j++) acc[i][j] = (f32x4){0.f, 0.f, 0.f, 0.f};
    for (int k0 = 0; k0 < D_N; k0 += 32) {
      __syncthreads();
      stage16(&z[(size_t)(row0 + srow) * D_N + k0 + skq], &Ah[srow][skq], &Al[srow][skq]);
      stage16(&w[(size_t)(c0   + srow) * D_N + k0 + skq], &Bh[srow][skq], &Bl[srow][skq]);
      __syncthreads();
      bf16x8 ah[4], al[4], bh[4], bl[4];
      #pragma unroll
      for (int i = 0; i < 4; i++) {
        ah[i] = *(const bf16x8*)&Ah[wm*64 + i*16 + l15][lg*8];
        al[i] = *(const bf16x8*)&Al[wm*64 + i*16 + l15][lg*8];
        bh[i] = *(const bf16x8*)&Bh[wn*64 + i*16 + l15][lg*8];
        bl[i] = *(const bf16x8*)&Bl[wn*64 + i*16 + l15][lg*8];
      }
      #pragma unroll
      for (int i = 0; i < 4; i++)
        #pragma unroll
        for (int j = 0; j < 4; j++) {
          acc[i][j] = __builtin_amdgcn_mfma_f32_16x16x32_bf16(ah[i], bh[j], acc[i][j], 0, 0, 0);
          acc[i][j] = __builtin_amdgcn_mfma_f32_16x16x32_bf16(ah[i], bl[j], acc[i][j], 0, 0, 0);
          acc[i][j] = __builtin_amdgcn_mfma_f32_16x16x32_bf16(al[i], bh[j], acc[i][j], 0, 0, 0);
        }
    }
    float wq[4];
    #pragma unroll
    for (int j = 0; j < 4; j++) wq[j] = wsq[c0 + wn*64 + j*16 + l15];
    #pragma unroll
    for (int i = 0; i < 4; i++)
      #pragma unroll
      for (int r = 0; r < 4; r++) {
        const int e = i * 4 + r;
        #pragma unroll
        for (int j = 0; j < 4; j++) {
          float dist = wq[j] - 2.0f * acc[i][j][r];
          if (dist < rmin[e]) { rmin[e] = dist; ridx[e] = c0 + wn*64 + j*16 + l15; }
        }
      }
  }
  #pragma unroll
  for (int e = 0; e < 16; e++) {
    float v = rmin[e]; int ix = ridx[e];
    #pragma unroll
    for (int m = 1; m < 16; m <<= 1) {
      float ov = __shfl_xor(v, m, 64);
      int   oi = __shfl_xor(ix, m, 64);
      if (ov < v || (ov == v && oi < ix)) { v = ov; ix = oi; }
    }
    rmin[e] = v; ridx[e] = ix;
  }
  const int s = l15;
  float bv = 0.f; int bi = 0;
  #pragma unroll
  for (int e = 0; e < 16; e++) {
    bool p = (e == s);
    bv = p ? rmin[e] : bv;
    bi = p ? ridx[e] : bi;
  }
  unsigned u = __float_as_uint(bv);
  u = (u & 0x80000000u) ? ~u : (u | 0x80000000u);
  unsigned long long key = ((unsigned long long)u << 32) | (unsigned)bi;
  atomicMin(&packed[row0 + wm*64 + (s >> 2)*16 + lg*4 + (s & 3)], key);
}

// ------------------------------------------- counting-sort segment-sum ----
__global__ __launch_bounds__(256) void count_kernel(
    const unsigned long long* __restrict__ packed, int* __restrict__ cnt,
    float* __restrict__ idxout) {
  int row = blockIdx.x * 256 + threadIdx.x;
  int idx = (int)(packed[row] & 0xFFFFFFFFull);
  idxout[row] = (float)idx;
  atomicAdd(&cnt[idx], 1);
}

__global__ __launch_bounds__(256) void scan_kernel(const int* __restrict__ cnt,
                                                   int* __restrict__ offs,
                                                   int* __restrict__ cursor) {
  int t = threadIdx.x;
  int base = t * 32;
  int local[32];
  int s = 0;
  #pragma unroll
  for (int i = 0; i < 32; i++) { local[i] = s; s += cnt[base + i]; }
  __shared__ int ps[257];
  ps[t + 1] = s;
  if (t == 0) ps[0] = 0;
  __syncthreads();
  if (t == 0) { for (int i = 1; i <= 256; i++) ps[i] += ps[i - 1]; }
  __syncthreads();
  int e = ps[t];
  #pragma unroll
  for (int i = 0; i < 32; i++) {
    int o = e + local[i];
    offs[base + i] = o; cursor[base + i] = o;
  }
  if (t == 255) offs[8192] = ps[256];
}

__global__ __launch_bounds__(256) void scatter_ids(
    const unsigned long long* __restrict__ packed, int* __restrict__ cursor,
    int* __restrict__ rowlist) {
  int row = blockIdx.x * 256 + threadIdx.x;
  int idx = (int)(packed[row] & 0xFFFFFFFFull);
  int pos = atomicAdd(&cursor[idx], 1);
  rowlist[pos] = row;
}

// nedw[k] = 0.99*edw[k] + 0.01*sum(z rows with idx==k); ncs[k] fused too.
__global__ __launch_bounds__(256) void seg_accum(
    const float* __restrict__ z, const float* __restrict__ edw,
    const float* __restrict__ ecs, const int* __restrict__ offs,
    const int* __restrict__ rowlist, float* __restrict__ nedw_out,
    float* __restrict__ ncs_out) {
  int k = blockIdx.x, t = threadIdx.x;
  int s0 = offs[k], s1 = offs[k + 1];
  float ax = 0.f, ay = 0.f;
  for (int r = s0; r < s1; r++) {
    int row = rowlist[r];
    float2 zv = *(const float2*)&z[(size_t)row * D_N + t * 2];
    ax += zv.x; ay += zv.y;
  }
  float2 ev = *(const float2*)&edw[(size_t)k * D_N + t * 2];
  float2 o;
  o.x = EMA * ev.x + ONE_M_EMA * ax;
  o.y = EMA * ev.y + ONE_M_EMA * ay;
  *(float2*)&nedw_out[(size_t)k * D_N + t * 2] = o;
  if (t == 0) ncs_out[k] = EMA * ecs[k] + ONE_M_EMA * (float)(s1 - s0);
}

// ------------------------------------------------ quantize + loss partial --
__global__ __launch_bounds__(256) void quant_loss(
    const float* __restrict__ z, const float* __restrict__ w,
    const unsigned long long* __restrict__ packed,
    float* __restrict__ qout, float* __restrict__ lpart) {
  int row = blockIdx.x, t = threadIdx.x;
  int idx = (int)(packed[row] & 0xFFFFFFFFull);
  float2 zv = *(const float2*)&z[(size_t)row * D_N + t * 2];
  float2 wv = *(const float2*)&w[(size_t)idx * D_N + t * 2];
  float2 q;
  q.x = zv.x + (wv.x - zv.x);
  q.y = zv.y + (wv.y - zv.y);
  *(float2*)&qout[(size_t)row * D_N + t * 2] = q;
  float dx = zv.x - wv.x, dy = zv.y - wv.y;
  float s = dx * dx + dy * dy;
  #pragma unroll
  for (int off = 32; off; off >>= 1) s += __shfl_down(s, off);
  __shared__ float part[4];
  if ((t & 63) == 0) part[t >> 6] = s;
  __syncthreads();
  if (t == 0) lpart[row] = part[0] + part[1] + part[2] + part[3];
}

// ------------------------------------------------------------- reductions -
__global__ __launch_bounds__(256) void reduce2(const float* __restrict__ ncs_out,
                                               const float* __restrict__ lpart,
                                               float* __restrict__ nsum,
                                               float* __restrict__ loss_sum) {
  int t = threadIdx.x;
  float s1 = 0.f, s2 = 0.f;
  for (int i = t; i < K_N; i += 256) s1 += ncs_out[i];
  for (int i = t; i < B_N; i += 256) s2 += lpart[i];
  #pragma unroll
  for (int off = 32; off; off >>= 1) {
    s1 += __shfl_down(s1, off);
    s2 += __shfl_down(s2, off);
  }
  __shared__ float p1[4], p2[4];
  if ((t & 63) == 0) { p1[t >> 6] = s1; p2[t >> 6] = s2; }
  __syncthreads();
  if (t == 0) {
    nsum[0]     = p1[0] + p1[1] + p1[2] + p1[3];
    loss_sum[0] = p2[0] + p2[1] + p2[2] + p2[3];
  }
}

// fallback-path kernels (atomic scatter, loss atomic)
__global__ __launch_bounds__(256) void gather_scatter(
    const float* __restrict__ z, const float* __restrict__ w,
    const unsigned long long* __restrict__ packed,
    float* __restrict__ qout, float* __restrict__ idxout,
    float* __restrict__ ncs_out, float* __restrict__ nedw_out,
    float* __restrict__ loss_sum) {
  int row = blockIdx.x;
  int t   = threadIdx.x;
  int idx = (int)(packed[row] & 0xFFFFFFFFull);
  float2 zv = *(const float2*)&z[(size_t)row * D_N + t * 2];
  float2 wv = *(const float2*)&w[(size_t)idx * D_N + t * 2];
  float2 q;
  q.x = zv.x + (wv.x - zv.x);
  q.y = zv.y + (wv.y - zv.y);
  *(float2*)&qout[(size_t)row * D_N + t * 2] = q;
  float dx = zv.x - wv.x, dy = zv.y - wv.y;
  float s = dx*dx + dy*dy;
  #pragma unroll
  for (int off = 32; off; off >>= 1) s += __shfl_down(s, off);
  __shared__ float part[4];
  if ((t & 63) == 0) part[t >> 6] = s;
  __syncthreads();
  if (t == 0) {
    atomicAdd(loss_sum, part[0] + part[1] + part[2] + part[3]);
    atomicAdd(&ncs_out[idx], ONE_M_EMA);
    idxout[row] = (float)idx;
  }
  atomicAdd(&nedw_out[(size_t)idx * D_N + t*2],     ONE_M_EMA * zv.x);
  atomicAdd(&nedw_out[(size_t)idx * D_N + t*2 + 1], ONE_M_EMA * zv.y);
}

__global__ __launch_bounds__(256) void reduce_n(const float* __restrict__ ncs_out,
                                                float* __restrict__ nsum) {
  int t = threadIdx.x;
  float s = 0.f;
  for (int i = t; i < K_N; i += 256) s += ncs_out[i];
  #pragma unroll
  for (int off = 32; off; off >>= 1) s += __shfl_down(s, off);
  __shared__ float part[4];
  if ((t & 63) == 0) part[t >> 6] = s;
  __syncthreads();
  if (t == 0) nsum[0] = part[0] + part[1] + part[2] + part[3];
}

__global__ __launch_bounds__(256) void finalize(
    const float* __restrict__ ncs_out, const float* __restrict__ nedw_out,
    float* __restrict__ nw_out, const float* __restrict__ nsum,
    const float* __restrict__ loss_sum, float* __restrict__ loss_out) {
  size_t i = (size_t)blockIdx.x * 256 + threadIdx.x;
  float n = nsum[0];
  int k = (int)(i >> 9);
  float nv = ncs_out[k];
  float cs = (nv + EPS_) / (n + K_N * EPS_) * n;
  nw_out[i] = nedw_out[i] / cs;
  if (i == 0) loss_out[0] = CCOST * loss_sum[0] / (float)((size_t)B_N * D_N);
}

// ------------------------------------------------------------------ launch -
extern "C" void kernel_launch(void* const* d_in, const int* in_sizes, int n_in,
                              void* d_out, int out_size, void* d_ws, size_t ws_size,
                              hipStream_t stream) {
  const float* z   = (const float*)d_in[0];
  const float* w   = (const float*)d_in[1];
  const float* ecs = (const float*)d_in[2];
  const float* edw = (const float*)d_in[3];

  float* out      = (float*)d_out;
  float* qout     = out;
  float* idxout   = out + (size_t)B_N * D_N;
  float* loss_out = idxout + B_N;
  float* nw_out   = loss_out + 1;
  float* ncs_out  = nw_out + (size_t)K_N * D_N;
  float* nedw_out = ncs_out + K_N;

  unsigned long long* packed = (unsigned long long*)d_ws;
  float* wsq      = (float*)((char*)d_ws + 262144);
  float* loss_sum = (float*)((char*)d_ws + 294912);
  float* nsum     = loss_sum + 1;

  hipMemsetAsync(d_ws, 0xFF, 262144, stream);
  hipMemsetAsync((void*)loss_sum, 0, 8, stream);

  prep_kernel<<<2048, 256, 0, stream>>>(w, ecs, wsq, ncs_out);

  if (ws_size >= WS_NEED) {
    ushort* zp  = (ushort*)((char*)d_ws + ZP_OFF);
    ushort* wp  = (ushort*)((char*)d_ws + WP_OFF);
    int* cnt    = (int*)((char*)d_ws + CNT_OFF);
    int* offs   = (int*)((char*)d_ws + OFFS_OFF);
    int* cursor = (int*)((char*)d_ws + CURS_OFF);
    int* rowl   = (int*)((char*)d_ws + ROWL_OFF);
    float* lpart= (float*)((char*)d_ws + LPART_OFF);

    split_pack<<<8192, 256, 0, stream>>>(z, zp, 0);
    split_pack<<<2048, 256, 0, stream>>>(w, wp, 1);
    score3<<<dim3(B_N / 128, KSPLIT), 256, 0, stream>>>(zp, wp, wsq, packed);
    // aux arrays alias zp (dead after score3) -> init only now
    hipMemsetAsync((void*)cnt, 0, K_N * sizeof(int), stream);
    count_kernel<<<B_N / 256, 256, 0, stream>>>(packed, cnt, idxout);
    scan_kernel<<<1, 256, 0, stream>>>(cnt, offs, cursor);
    scatter_ids<<<B_N / 256, 256, 0, stream>>>(packed, cursor, rowl);
    seg_accum<<<K_N, 256, 0, stream>>>(z, edw, ecs, offs, rowl, nedw_out, ncs_out);
    quant_loss<<<B_N, 256, 0, stream>>>(z, w, packed, qout, lpart);
    reduce2<<<1, 256, 0, stream>>>(ncs_out, lpart, nsum, loss_sum);
  } else {
    prep_nedw<<<4096, 256, 0, stream>>>((const float4*)edw, (float4*)nedw_out);
    score_argmin_mfma<<<dim3(B_N / 128, KSPLIT), 256, 0, stream>>>(z, w, wsq, packed);
    gather_scatter<<<B_N, 256, 0, stream>>>(z, w, packed, qout, idxout,
                                            ncs_out, nedw_out, loss_sum);
    reduce_n<<<1, 256, 0, stream>>>(ncs_out, nsum);
  }

  finalize<<<K_N * D_N / 256, 256, 0, stream>>>(ncs_out, nedw_out, nw_out,
                                                nsum, loss_sum, loss_out);
}